// Round 5
// baseline (608.586 us; speedup 1.0000x reference)
//
#include <hip/hip_runtime.h>

#define NN 100000      // nodes
#define NE 1600000     // edges
#define NBLK 391       // ceil(NN/256) scan blocks
#define NBIN 782       // ceil(NN/128) scatter bins
#define CAP  3072      // max edges per bin sortbin handles in LDS (+22 sigma)
// dims: NODE_IN=64, EDGE_DIM=32, NODE_OUT=64, concat=96, fused K=160

// ws layout (4B units)
#define OFF_CNT   0                    // NN    int   in-degree (memset 0)
#define OFF_RS    100000               // NN+1  int   CSR row_start (exclusive)
#define OFF_CUR   200004               // NBIN  int   bin cursors
#define OFF_BSUM  300008               // 512   int   per-block sums -> exclusive offsets
#define OFF_EINFO 300520               // NE*2  int2  (src|dl<<20, eid), bin-staged then sorted
#define OFF_G     3500520              // NN*96 float concat sums (16B aligned)
#define OFF_WCOMB 13100520             // 160*64 float [Wa_top(64x64); Wm@Wa_bot(96x64)]
#define OFF_BMW   13110760             // 64    float bm@Wa_bot
#define OFF_INV   13110824             // NN    float 1/cnt or 0
#define OFF_MASK  13210824             // NN    float cnt>0 ? 1 : 0

// ---- 1. histogram of dst (8 edges/thread, fire-and-forget atomics) ------
__global__ __launch_bounds__(256) void k_hist(const int4* __restrict__ dst4,
                                              int* __restrict__ cnt) {
  int t = blockIdx.x * 256 + threadIdx.x;
  if (t >= NE / 8) return;
  int4 d0 = dst4[t * 2], d1 = dst4[t * 2 + 1];
  atomicAdd(&cnt[d0.x], 1); atomicAdd(&cnt[d0.y], 1);
  atomicAdd(&cnt[d0.z], 1); atomicAdd(&cnt[d0.w], 1);
  atomicAdd(&cnt[d1.x], 1); atomicAdd(&cnt[d1.y], 1);
  atomicAdd(&cnt[d1.z], 1); atomicAdd(&cnt[d1.w], 1);
}

// ---- 2a. per-block inclusive scan + block sums --------------------------
__global__ __launch_bounds__(256) void k_scan1(const int* __restrict__ cnt,
                                               int* __restrict__ rs_incl,
                                               int* __restrict__ bsum) {
  __shared__ int s[256];
  int t = threadIdx.x, n = blockIdx.x * 256 + t;
  int v = (n < NN) ? cnt[n] : 0;
  s[t] = v; __syncthreads();
#pragma unroll
  for (int off = 1; off < 256; off <<= 1) {
    int x = (t >= off) ? s[t - off] : 0;
    __syncthreads();
    s[t] += x;
    __syncthreads();
  }
  if (n < NN) rs_incl[n] = s[t];
  if (t == 255) bsum[blockIdx.x] = s[255];
}

// ---- 2b. scan of block sums (one block of 512) --------------------------
__global__ __launch_bounds__(512) void k_scan2(int* __restrict__ bsum) {
  __shared__ int s[512];
  int t = threadIdx.x;
  int v = (t < NBLK) ? bsum[t] : 0;
  s[t] = v; __syncthreads();
#pragma unroll
  for (int off = 1; off < 512; off <<= 1) {
    int x = (t >= off) ? s[t - off] : 0;
    __syncthreads();
    s[t] += x;
    __syncthreads();
  }
  if (t < NBLK) bsum[t] = s[t] - v;   // exclusive
}

// ---- 2c. finalize row_start + bin cursors + invc/mask -------------------
__global__ __launch_bounds__(256) void k_scan3(const int* __restrict__ cnt,
                                               const int* __restrict__ bsum,
                                               int* __restrict__ rs,
                                               int* __restrict__ bincur,
                                               float* __restrict__ invc,
                                               float* __restrict__ mask) {
  int t = threadIdx.x, n = blockIdx.x * 256 + t;
  if (n < NN) {
    int c = cnt[n];
    int excl = bsum[blockIdx.x] + rs[n] - c;
    rs[n] = excl;
    if ((n & 127) == 0) bincur[n >> 7] = excl;
    invc[n] = c ? 1.f / (float)c : 0.f;
    mask[n] = c ? 1.f : 0.f;
  }
  if (n == 0) rs[NN] = NE;
}

// ---- 3a. bin scatter: 782 hot cursors, line-dense staged writes ---------
__global__ __launch_bounds__(256) void k_binscatter(
    const int4* __restrict__ src4, const int4* __restrict__ dst4,
    int* __restrict__ bincur, int2* __restrict__ einfo) {
  int t = blockIdx.x * 256 + threadIdx.x;
  if (t >= NE / 4) return;
  int4 s = src4[t], d = dst4[t];
  int e = t * 4;
  int p0 = atomicAdd(&bincur[d.x >> 7], 1);
  int p1 = atomicAdd(&bincur[d.y >> 7], 1);
  int p2 = atomicAdd(&bincur[d.z >> 7], 1);
  int p3 = atomicAdd(&bincur[d.w >> 7], 1);
  einfo[p0] = make_int2(s.x | ((d.x & 127) << 20), e);
  einfo[p1] = make_int2(s.y | ((d.y & 127) << 20), e + 1);
  einfo[p2] = make_int2(s.z | ((d.z & 127) << 20), e + 2);
  einfo[p3] = make_int2(s.w | ((d.w & 127) << 20), e + 3);
}

// ---- 3b. in-place LDS counting sort of each bin into exact CSR order ----
__global__ __launch_bounds__(256) void k_sortbin(const int* __restrict__ rs,
                                                 int2* __restrict__ einfo) {
  __shared__ int hist[128];
  __shared__ int excl[128];
  __shared__ int2 buf[CAP];
  int b = blockIdx.x, t = threadIdx.x;
  int base = rs[b * 128];
  int endNode = (b + 1) * 128; if (endNode > NN) endNode = NN;
  int nE = rs[endNode] - base;
  int nS = nE < CAP ? nE : CAP;       // statistically nE << CAP always
  if (t < 128) hist[t] = 0;
  __syncthreads();
  for (int i = t; i < nS; i += 256) {  // load + per-node count
    int2 v = einfo[base + i];
    buf[i] = v;
    atomicAdd(&hist[(v.x >> 20) & 127], 1);
  }
  __syncthreads();
  if (t < 128) excl[t] = hist[t];
  __syncthreads();
#pragma unroll
  for (int off = 1; off < 128; off <<= 1) {  // Hillis-Steele inclusive scan
    int x = 0;
    if (t < 128 && t >= off) x = excl[t - off];
    __syncthreads();
    if (t < 128) excl[t] += x;
    __syncthreads();
  }
  if (t < 128) hist[t] = t ? excl[t - 1] : 0;   // reuse hist as write cursor
  __syncthreads();
  for (int i = t; i < nS; i += 256) {  // place in CSR order, strip packing
    int2 v = buf[i];
    int dl = (v.x >> 20) & 127;
    int p = atomicAdd(&hist[dl], 1);
    einfo[base + p] = make_int2(v.x & 0xFFFFF, v.y);
  }
  for (int i = nS + t; i < nE; i += 256)  // unreachable overflow: keep data sane
    atomicAnd((int*)&einfo[base + i].x, 0xFFFFF);
}

// ---- 4. gather: one wave per node, lane = feature dim -------------------
__global__ __launch_bounds__(256) void k_gather(
    const float* __restrict__ nf, const float* __restrict__ ef,
    const int2* __restrict__ einfo, const int* __restrict__ rs,
    float* __restrict__ g) {
  int wid = threadIdx.x >> 6, lane = threadIdx.x & 63;
  int node = blockIdx.x * 4 + wid;          // 25000*4 == NN exactly
  int beg = rs[node], end = rs[node + 1];
  int deg = end - beg;
  bool hi = lane >= 32;
  int l32 = lane & 31;
  float a0 = 0.f, a1 = 0.f;
  for (int base = 0; base < deg; base += 64) {
    int nb = deg - base; if (nb > 64) nb = 64;
    int2 info = (lane < nb) ? einfo[beg + base + lane] : make_int2(0, 0);
    int j = 0;
    for (; j + 8 <= nb; j += 8) {
      int s0 = __shfl(info.x, j);
      int s1 = __shfl(info.x, j + 1);
      int s2 = __shfl(info.x, j + 2);
      int s3 = __shfl(info.x, j + 3);
      int s4 = __shfl(info.x, j + 4);
      int s5 = __shfl(info.x, j + 5);
      int s6 = __shfl(info.x, j + 6);
      int s7 = __shfl(info.x, j + 7);
      int ep0 = __shfl(info.y, hi ? j + 1 : j);
      int ep1 = __shfl(info.y, hi ? j + 3 : j + 2);
      int ep2 = __shfl(info.y, hi ? j + 5 : j + 4);
      int ep3 = __shfl(info.y, hi ? j + 7 : j + 6);
      float v0 = nf[s0 * 64 + lane];
      float v1 = nf[s1 * 64 + lane];
      float v2 = nf[s2 * 64 + lane];
      float v3 = nf[s3 * 64 + lane];
      float v4 = nf[s4 * 64 + lane];
      float v5 = nf[s5 * 64 + lane];
      float v6 = nf[s6 * 64 + lane];
      float v7 = nf[s7 * 64 + lane];
      float w0 = ef[ep0 * 32 + l32];
      float w1 = ef[ep1 * 32 + l32];
      float w2 = ef[ep2 * 32 + l32];
      float w3 = ef[ep3 * 32 + l32];
      a0 += v0 + v1 + v2 + v3 + v4 + v5 + v6 + v7;
      a1 += w0 + w1 + w2 + w3;
    }
    for (; j + 2 <= nb; j += 2) {
      int s0 = __shfl(info.x, j);
      int s1 = __shfl(info.x, j + 1);
      int ep = __shfl(info.y, hi ? j + 1 : j);
      float v0 = nf[s0 * 64 + lane];
      float v1 = nf[s1 * 64 + lane];
      float w0 = ef[ep * 32 + l32];
      a0 += v0 + v1;
      a1 += w0;
    }
    if (j < nb) {
      int s0 = __shfl(info.x, j);
      int e0 = __shfl(info.y, j);
      a0 += nf[s0 * 64 + lane];
      if (!hi) a1 += ef[e0 * 32 + l32];
    }
  }
  a1 += __shfl_down(a1, 32);     // fold odd-edge ef sums (upper half) into lower
  g[node * 96 + lane] = a0;
  if (!hi) g[node * 96 + 64 + l32] = a1;
}

// ---- precompute fused weights: Wcomb = [Wa[0:64]; Wm @ Wa[64:128]] ------
__global__ __launch_bounds__(256) void k_pre1(
    const float* __restrict__ Wm, const float* __restrict__ bm,
    const float* __restrict__ Wa, float* __restrict__ Wcomb,
    float* __restrict__ bmW) {
  int b = blockIdx.x, t = threadIdx.x;
  if (b < 24) {                       // 24*256 = 6144 = 96*64 fused entries
    int o = b * 256 + t;
    int k = o >> 6, j = o & 63;
    float acc = 0.f;
    for (int kk = 0; kk < 64; ++kk)
      acc += Wm[k * 64 + kk] * Wa[(64 + kk) * 64 + j];
    Wcomb[(64 + k) * 64 + j] = acc;
  } else {
    for (int i = t; i < 64 * 64; i += 256) Wcomb[i] = Wa[i];  // top block copy
    if (t < 64) {
      float acc = 0.f;
      for (int kk = 0; kk < 64; ++kk) acc += bm[kk] * Wa[(64 + kk) * 64 + t];
      bmW[t] = acc;
    }
  }
}

// ---- fused node GEMM: out = relu([nf | g*inv] @ Wcomb + ba + mask*bmW) --
__global__ __launch_bounds__(256) void k_main(
    const float4* __restrict__ nf4, const float4* __restrict__ g4,
    const float* __restrict__ invc, const float* __restrict__ mask,
    const float4* __restrict__ Wcomb4, const float* __restrict__ bmW,
    const float* __restrict__ ba, float* __restrict__ out) {
  __shared__ float sA[128 * 33];   // [node][k] pad 33 -> a-reads conflict-free
  __shared__ float sB[32 * 64];    // [k][j]
  int tid = threadIdx.x;
  int ty = tid >> 3, tx = tid & 7;
  int nbase = blockIdx.x * 128;
  float acc[4][8];
#pragma unroll
  for (int r = 0; r < 4; ++r)
#pragma unroll
    for (int e = 0; e < 8; ++e) acc[r][e] = 0.f;

  for (int c = 0; c < 5; ++c) {
#pragma unroll
    for (int i = 0; i < 4; ++i) {
      int f = i * 256 + tid;          // 0..1023 float4s
      int nl = f >> 3, q = f & 7;
      int node = nbase + nl; if (node > NN - 1) node = NN - 1;
      float4 v;
      if (c < 2) {
        v = nf4[node * 16 + c * 8 + q];
      } else {
        v = g4[node * 24 + (c - 2) * 8 + q];
        float iv = invc[node];
        v.x *= iv; v.y *= iv; v.z *= iv; v.w *= iv;
      }
      float* p = &sA[nl * 33 + q * 4];
      p[0] = v.x; p[1] = v.y; p[2] = v.z; p[3] = v.w;
    }
#pragma unroll
    for (int i = 0; i < 2; ++i) {
      int f = i * 256 + tid;          // 0..511 float4s
      int kk = f >> 4, j4 = f & 15;
      float4 w = Wcomb4[(c * 32 + kk) * 16 + j4];
      *(float4*)&sB[kk * 64 + j4 * 4] = w;
    }
    __syncthreads();
#pragma unroll 8
    for (int kk = 0; kk < 32; ++kk) {
      float4 b0 = *(const float4*)&sB[kk * 64 + tx * 8];
      float4 b1 = *(const float4*)&sB[kk * 64 + tx * 8 + 4];
#pragma unroll
      for (int r = 0; r < 4; ++r) {
        float a = sA[(ty * 4 + r) * 33 + kk];
        acc[r][0] += a * b0.x; acc[r][1] += a * b0.y;
        acc[r][2] += a * b0.z; acc[r][3] += a * b0.w;
        acc[r][4] += a * b1.x; acc[r][5] += a * b1.y;
        acc[r][6] += a * b1.z; acc[r][7] += a * b1.w;
      }
    }
    __syncthreads();
  }
  float4 ba0 = ((const float4*)ba)[tx * 2];
  float4 ba1 = ((const float4*)ba)[tx * 2 + 1];
  float4 bw0 = ((const float4*)bmW)[tx * 2];
  float4 bw1 = ((const float4*)bmW)[tx * 2 + 1];
#pragma unroll
  for (int r = 0; r < 4; ++r) {
    int node = nbase + ty * 4 + r;
    if (node < NN) {
      float mk = mask[node];
      float4 o0, o1;
      o0.x = acc[r][0] + ba0.x + mk * bw0.x;
      o0.y = acc[r][1] + ba0.y + mk * bw0.y;
      o0.z = acc[r][2] + ba0.z + mk * bw0.z;
      o0.w = acc[r][3] + ba0.w + mk * bw0.w;
      o1.x = acc[r][4] + ba1.x + mk * bw1.x;
      o1.y = acc[r][5] + ba1.y + mk * bw1.y;
      o1.z = acc[r][6] + ba1.z + mk * bw1.z;
      o1.w = acc[r][7] + ba1.w + mk * bw1.w;
      o0.x = fmaxf(o0.x, 0.f); o0.y = fmaxf(o0.y, 0.f);
      o0.z = fmaxf(o0.z, 0.f); o0.w = fmaxf(o0.w, 0.f);
      o1.x = fmaxf(o1.x, 0.f); o1.y = fmaxf(o1.y, 0.f);
      o1.z = fmaxf(o1.z, 0.f); o1.w = fmaxf(o1.w, 0.f);
      *(float4*)&out[node * 64 + tx * 8] = o0;
      *(float4*)&out[node * 64 + tx * 8 + 4] = o1;
    }
  }
}

extern "C" void kernel_launch(void* const* d_in, const int* in_sizes, int n_in,
                              void* d_out, int out_size, void* d_ws, size_t ws_size,
                              hipStream_t stream) {
  const float* nf = (const float*)d_in[0];
  const float* ef = (const float*)d_in[1];
  const int*   src = (const int*)d_in[2];
  const int*   dst = (const int*)d_in[3];
  const float* Wm = (const float*)d_in[4];
  const float* bm = (const float*)d_in[5];
  const float* Wa = (const float*)d_in[6];
  const float* ba = (const float*)d_in[7];
  int*   wsi = (int*)d_ws;
  float* wsf = (float*)d_ws;
  int*   cnt    = wsi + OFF_CNT;
  int*   rs     = wsi + OFF_RS;
  int*   bincur = wsi + OFF_CUR;
  int*   bsum   = wsi + OFF_BSUM;
  int2*  einfo  = (int2*)(wsi + OFF_EINFO);
  float* g      = wsf + OFF_G;
  float* Wcomb  = wsf + OFF_WCOMB;
  float* bmW    = wsf + OFF_BMW;
  float* invc   = wsf + OFF_INV;
  float* mask   = wsf + OFF_MASK;
  float* out = (float*)d_out;

  hipMemsetAsync(cnt, 0, (size_t)NN * sizeof(int), stream);   // only histogram needs zeroing

  k_pre1<<<25, 256, 0, stream>>>(Wm, bm, Wa, Wcomb, bmW);
  k_hist<<<(NE / 8 + 255) / 256, 256, 0, stream>>>((const int4*)dst, cnt);
  k_scan1<<<NBLK, 256, 0, stream>>>(cnt, rs, bsum);
  k_scan2<<<1, 512, 0, stream>>>(bsum);
  k_scan3<<<NBLK, 256, 0, stream>>>(cnt, bsum, rs, bincur, invc, mask);
  k_binscatter<<<(NE / 4 + 255) / 256, 256, 0, stream>>>(
      (const int4*)src, (const int4*)dst, bincur, einfo);
  k_sortbin<<<NBIN, 256, 0, stream>>>(rs, einfo);
  k_gather<<<NN / 4, 256, 0, stream>>>(nf, ef, einfo, rs, g);
  k_main<<<(NN + 127) / 128, 256, 0, stream>>>(
      (const float4*)nf, (const float4*)g, invc, mask,
      (const float4*)Wcomb, bmW, ba, out);
}

// Round 6
// 254.387 us; speedup vs baseline: 2.3924x; 2.3924x over previous
//
#include <hip/hip_runtime.h>

#define NN 100000      // nodes
#define NE 1600000     // edges
#define NBLK 391       // ceil(NN/256) scan blocks
#define NBIN 782       // ceil(NN/128) bins (128 nodes each)
#define CAP  3072      // max edges per bin sortbin handles in LDS (+22 sigma)
#define EPB  8192      // edges per partition block
#define NBLKE 196      // ceil(NE/EPB)
// dims: NODE_IN=64, EDGE_DIM=32, NODE_OUT=64, concat=96, fused K=160

// ws layout (4B units)
#define OFF_CNT   0                    // NN    int   in-degree (memset 0)
#define OFF_RS    100000               // NN+1  int   CSR row_start (exclusive)
#define OFF_BSUM  200004               // 512   int   per-block sums -> exclusive offsets
#define OFF_EINFO 300520               // NE*2  int2  (src|dl<<20, eid) partitioned by bin
#define OFF_G     3500520              // NN*96 float concat sums (16B aligned)
#define OFF_HM    OFF_G                // NBLKE*NBIN int  hist matrix   (inside G, dead after bscan)
#define OFF_OM    (OFF_G + 153272)     // NBLKE*NBIN int  offset matrix (inside G, dead after bplace)
#define OFF_WCOMB 13100520             // 160*64 float [Wa_top(64x64); Wm@Wa_bot(96x64)]
#define OFF_BMW   13110760             // 64    float bm@Wa_bot
#define OFF_INV   13110824             // NN    float 1/cnt or 0
#define OFF_MASK  13210824             // NN    float cnt>0 ? 1 : 0

// ---- 1. per-node histogram of dst (8 edges/thread, fire-and-forget) -----
__global__ __launch_bounds__(256) void k_hist(const int4* __restrict__ dst4,
                                              int* __restrict__ cnt) {
  int t = blockIdx.x * 256 + threadIdx.x;
  if (t >= NE / 8) return;
  int4 d0 = dst4[t * 2], d1 = dst4[t * 2 + 1];
  atomicAdd(&cnt[d0.x], 1); atomicAdd(&cnt[d0.y], 1);
  atomicAdd(&cnt[d0.z], 1); atomicAdd(&cnt[d0.w], 1);
  atomicAdd(&cnt[d1.x], 1); atomicAdd(&cnt[d1.y], 1);
  atomicAdd(&cnt[d1.z], 1); atomicAdd(&cnt[d1.w], 1);
}

// ---- 2a. per-block inclusive scan + block sums --------------------------
__global__ __launch_bounds__(256) void k_scan1(const int* __restrict__ cnt,
                                               int* __restrict__ rs_incl,
                                               int* __restrict__ bsum) {
  __shared__ int s[256];
  int t = threadIdx.x, n = blockIdx.x * 256 + t;
  int v = (n < NN) ? cnt[n] : 0;
  s[t] = v; __syncthreads();
#pragma unroll
  for (int off = 1; off < 256; off <<= 1) {
    int x = (t >= off) ? s[t - off] : 0;
    __syncthreads();
    s[t] += x;
    __syncthreads();
  }
  if (n < NN) rs_incl[n] = s[t];
  if (t == 255) bsum[blockIdx.x] = s[255];
}

// ---- 2b. scan of block sums (one block of 512) --------------------------
__global__ __launch_bounds__(512) void k_scan2(int* __restrict__ bsum) {
  __shared__ int s[512];
  int t = threadIdx.x;
  int v = (t < NBLK) ? bsum[t] : 0;
  s[t] = v; __syncthreads();
#pragma unroll
  for (int off = 1; off < 512; off <<= 1) {
    int x = (t >= off) ? s[t - off] : 0;
    __syncthreads();
    s[t] += x;
    __syncthreads();
  }
  if (t < NBLK) bsum[t] = s[t] - v;   // exclusive
}

// ---- 2c. finalize row_start + invc/mask ---------------------------------
__global__ __launch_bounds__(256) void k_scan3(const int* __restrict__ cnt,
                                               const int* __restrict__ bsum,
                                               int* __restrict__ rs,
                                               float* __restrict__ invc,
                                               float* __restrict__ mask) {
  int t = threadIdx.x, n = blockIdx.x * 256 + t;
  if (n < NN) {
    int c = cnt[n];
    int excl = bsum[blockIdx.x] + rs[n] - c;
    rs[n] = excl;
    invc[n] = c ? 1.f / (float)c : 0.f;
    mask[n] = c ? 1.f : 0.f;
  }
  if (n == 0) rs[NN] = NE;
}

// ---- 3a. per-block bin histogram (radix partition phase A) --------------
__global__ __launch_bounds__(256) void k_bhist(const int4* __restrict__ dst4,
                                               int* __restrict__ hm) {
  __shared__ int h[NBIN];
  int b = blockIdx.x, t = threadIdx.x;
  for (int i = t; i < NBIN; i += 256) h[i] = 0;
  __syncthreads();
  int e0 = b * EPB;
#pragma unroll
  for (int i = 0; i < EPB / 1024; ++i) {
    int f = i * 256 + t;
    int e = e0 + f * 4;
    if (e < NE) {
      int4 d = dst4[(e0 >> 2) + f];
      atomicAdd(&h[d.x >> 7], 1);
      atomicAdd(&h[d.y >> 7], 1);
      atomicAdd(&h[d.z >> 7], 1);
      atomicAdd(&h[d.w >> 7], 1);
    }
  }
  __syncthreads();
  for (int i = t; i < NBIN; i += 256) hm[b * NBIN + i] = h[i];
}

// ---- 3b. column scan: om[b][bin] = rs[bin*128] + sum_{b'<b} hm[b'][bin] --
// one wave per bin; lanes cover the block dimension; shfl prefix scan.
__global__ __launch_bounds__(256) void k_bscan(const int* __restrict__ hm,
                                               const int* __restrict__ rs,
                                               int* __restrict__ om) {
  int w = (blockIdx.x * 256 + threadIdx.x) >> 6;   // wave id == bin
  int lane = threadIdx.x & 63;
  if (w >= NBIN) return;
  int carry = rs[w * 128];
  for (int base = 0; base < NBLKE; base += 64) {
    int b = base + lane;
    int v = (b < NBLKE) ? hm[b * NBIN + w] : 0;
    int inc = v;
#pragma unroll
    for (int off = 1; off < 64; off <<= 1) {
      int x = __shfl_up(inc, off);
      if (lane >= off) inc += x;
    }
    if (b < NBLKE) om[b * NBIN + w] = carry + inc - v;
    carry += __shfl(inc, 63);
  }
}

// ---- 3c. place: LDS counting-sort by bin, write line-dense runs ---------
__global__ __launch_bounds__(256) void k_bplace(
    const int4* __restrict__ src4, const int4* __restrict__ dst4,
    const int* __restrict__ om, int2* __restrict__ einfo) {
  __shared__ int2 buf[EPB];        // 64KB locally-sorted records
  __shared__ int hstart[1024];     // local exclusive bin starts (zero-padded)
  __shared__ int hcur[1024];       // counts, then cursors
  __shared__ int obase[NBIN];      // global run base for this block
  __shared__ int tscan[256];
  int b = blockIdx.x, t = threadIdx.x;
  int e0 = b * EPB;
  for (int i = t; i < 1024; i += 256) hcur[i] = 0;
  for (int i = t; i < NBIN; i += 256) obase[i] = om[b * NBIN + i];
  __syncthreads();
  // pass 1: local bin histogram
#pragma unroll
  for (int i = 0; i < EPB / 1024; ++i) {
    int f = i * 256 + t;
    int e = e0 + f * 4;
    if (e < NE) {
      int4 d = dst4[(e0 >> 2) + f];
      atomicAdd(&hcur[d.x >> 7], 1);
      atomicAdd(&hcur[d.y >> 7], 1);
      atomicAdd(&hcur[d.z >> 7], 1);
      atomicAdd(&hcur[d.w >> 7], 1);
    }
  }
  __syncthreads();
  // exclusive scan of 1024 buckets: 4/thread serial + Hillis-Steele on sums
  int base4 = t * 4;
  int v0 = hcur[base4], v1 = hcur[base4 + 1], v2 = hcur[base4 + 2], v3 = hcur[base4 + 3];
  int s = v0 + v1 + v2 + v3;
  tscan[t] = s;
  __syncthreads();
#pragma unroll
  for (int off = 1; off < 256; off <<= 1) {
    int x = (t >= off) ? tscan[t - off] : 0;
    __syncthreads();
    tscan[t] += x;
    __syncthreads();
  }
  int texcl = tscan[t] - s;
  hstart[base4]     = texcl;
  hstart[base4 + 1] = texcl + v0;
  hstart[base4 + 2] = texcl + v0 + v1;
  hstart[base4 + 3] = texcl + v0 + v1 + v2;
  __syncthreads();
  for (int i = t; i < 1024; i += 256) hcur[i] = hstart[i];
  __syncthreads();
  // pass 2: place records at sorted local positions (bin in y bits 21..31)
#pragma unroll
  for (int i = 0; i < EPB / 1024; ++i) {
    int f = i * 256 + t;
    int e = e0 + f * 4;
    if (e < NE) {
      int4 d = dst4[(e0 >> 2) + f];
      int4 sv = src4[(e0 >> 2) + f];
      int p0 = atomicAdd(&hcur[d.x >> 7], 1);
      int p1 = atomicAdd(&hcur[d.y >> 7], 1);
      int p2 = atomicAdd(&hcur[d.z >> 7], 1);
      int p3 = atomicAdd(&hcur[d.w >> 7], 1);
      buf[p0] = make_int2(sv.x | ((d.x & 127) << 20), (e)     | ((d.x >> 7) << 21));
      buf[p1] = make_int2(sv.y | ((d.y & 127) << 20), (e + 1) | ((d.y >> 7) << 21));
      buf[p2] = make_int2(sv.z | ((d.z & 127) << 20), (e + 2) | ((d.z >> 7) << 21));
      buf[p3] = make_int2(sv.w | ((d.w & 127) << 20), (e + 3) | ((d.w >> 7) << 21));
    }
  }
  __syncthreads();
  // write out: local-sorted order -> contiguous global runs per bin
  int nE = NE - e0; if (nE > EPB) nE = EPB;
  for (int i = t; i < nE; i += 256) {
    int2 r = buf[i];
    int bin = (unsigned)r.y >> 21;
    int pos = obase[bin] + (i - hstart[bin]);
    einfo[pos] = make_int2(r.x, r.y & 0x1FFFFF);
  }
}

// ---- 3d. in-place LDS counting sort of each bin into exact CSR order ----
__global__ __launch_bounds__(256) void k_sortbin(const int* __restrict__ rs,
                                                 int2* __restrict__ einfo) {
  __shared__ int hist[128];
  __shared__ int excl[128];
  __shared__ int2 buf[CAP];
  int b = blockIdx.x, t = threadIdx.x;
  int base = rs[b * 128];
  int endNode = (b + 1) * 128; if (endNode > NN) endNode = NN;
  int nE = rs[endNode] - base;
  int nS = nE < CAP ? nE : CAP;       // statistically nE << CAP always
  if (t < 128) hist[t] = 0;
  __syncthreads();
  for (int i = t; i < nS; i += 256) {  // load + per-node count
    int2 v = einfo[base + i];
    buf[i] = v;
    atomicAdd(&hist[(v.x >> 20) & 127], 1);
  }
  __syncthreads();
  if (t < 128) excl[t] = hist[t];
  __syncthreads();
#pragma unroll
  for (int off = 1; off < 128; off <<= 1) {  // Hillis-Steele inclusive scan
    int x = 0;
    if (t < 128 && t >= off) x = excl[t - off];
    __syncthreads();
    if (t < 128) excl[t] += x;
    __syncthreads();
  }
  if (t < 128) hist[t] = t ? excl[t - 1] : 0;   // reuse hist as write cursor
  __syncthreads();
  for (int i = t; i < nS; i += 256) {  // place in CSR order, strip packing
    int2 v = buf[i];
    int dl = (v.x >> 20) & 127;
    int p = atomicAdd(&hist[dl], 1);
    einfo[base + p] = make_int2(v.x & 0xFFFFF, v.y);
  }
  for (int i = nS + t; i < nE; i += 256)  // unreachable overflow: keep data sane
    atomicAnd((int*)&einfo[base + i].x, 0xFFFFF);
}

// ---- 4. gather: one wave per node, lane = feature dim -------------------
__global__ __launch_bounds__(256) void k_gather(
    const float* __restrict__ nf, const float* __restrict__ ef,
    const int2* __restrict__ einfo, const int* __restrict__ rs,
    float* __restrict__ g) {
  int wid = threadIdx.x >> 6, lane = threadIdx.x & 63;
  int node = blockIdx.x * 4 + wid;          // 25000*4 == NN exactly
  int beg = rs[node], end = rs[node + 1];
  int deg = end - beg;
  bool hi = lane >= 32;
  int l32 = lane & 31;
  float a0 = 0.f, a1 = 0.f;
  for (int base = 0; base < deg; base += 64) {
    int nb = deg - base; if (nb > 64) nb = 64;
    int2 info = (lane < nb) ? einfo[beg + base + lane] : make_int2(0, 0);
    int j = 0;
    for (; j + 8 <= nb; j += 8) {
      int s0 = __shfl(info.x, j);
      int s1 = __shfl(info.x, j + 1);
      int s2 = __shfl(info.x, j + 2);
      int s3 = __shfl(info.x, j + 3);
      int s4 = __shfl(info.x, j + 4);
      int s5 = __shfl(info.x, j + 5);
      int s6 = __shfl(info.x, j + 6);
      int s7 = __shfl(info.x, j + 7);
      int ep0 = __shfl(info.y, hi ? j + 1 : j);
      int ep1 = __shfl(info.y, hi ? j + 3 : j + 2);
      int ep2 = __shfl(info.y, hi ? j + 5 : j + 4);
      int ep3 = __shfl(info.y, hi ? j + 7 : j + 6);
      float v0 = nf[s0 * 64 + lane];
      float v1 = nf[s1 * 64 + lane];
      float v2 = nf[s2 * 64 + lane];
      float v3 = nf[s3 * 64 + lane];
      float v4 = nf[s4 * 64 + lane];
      float v5 = nf[s5 * 64 + lane];
      float v6 = nf[s6 * 64 + lane];
      float v7 = nf[s7 * 64 + lane];
      float w0 = ef[ep0 * 32 + l32];
      float w1 = ef[ep1 * 32 + l32];
      float w2 = ef[ep2 * 32 + l32];
      float w3 = ef[ep3 * 32 + l32];
      a0 += v0 + v1 + v2 + v3 + v4 + v5 + v6 + v7;
      a1 += w0 + w1 + w2 + w3;
    }
    for (; j + 2 <= nb; j += 2) {
      int s0 = __shfl(info.x, j);
      int s1 = __shfl(info.x, j + 1);
      int ep = __shfl(info.y, hi ? j + 1 : j);
      float v0 = nf[s0 * 64 + lane];
      float v1 = nf[s1 * 64 + lane];
      float w0 = ef[ep * 32 + l32];
      a0 += v0 + v1;
      a1 += w0;
    }
    if (j < nb) {
      int s0 = __shfl(info.x, j);
      int e0 = __shfl(info.y, j);
      a0 += nf[s0 * 64 + lane];
      if (!hi) a1 += ef[e0 * 32 + l32];
    }
  }
  a1 += __shfl_down(a1, 32);     // fold odd-edge ef sums (upper half) into lower
  g[node * 96 + lane] = a0;
  if (!hi) g[node * 96 + 64 + l32] = a1;
}

// ---- precompute fused weights: Wcomb = [Wa[0:64]; Wm @ Wa[64:128]] ------
__global__ __launch_bounds__(256) void k_pre1(
    const float* __restrict__ Wm, const float* __restrict__ bm,
    const float* __restrict__ Wa, float* __restrict__ Wcomb,
    float* __restrict__ bmW) {
  int b = blockIdx.x, t = threadIdx.x;
  if (b < 24) {                       // 24*256 = 6144 = 96*64 fused entries
    int o = b * 256 + t;
    int k = o >> 6, j = o & 63;
    float acc = 0.f;
    for (int kk = 0; kk < 64; ++kk)
      acc += Wm[k * 64 + kk] * Wa[(64 + kk) * 64 + j];
    Wcomb[(64 + k) * 64 + j] = acc;
  } else {
    for (int i = t; i < 64 * 64; i += 256) Wcomb[i] = Wa[i];  // top block copy
    if (t < 64) {
      float acc = 0.f;
      for (int kk = 0; kk < 64; ++kk) acc += bm[kk] * Wa[(64 + kk) * 64 + t];
      bmW[t] = acc;
    }
  }
}

// ---- fused node GEMM: out = relu([nf | g*inv] @ Wcomb + ba + mask*bmW) --
__global__ __launch_bounds__(256) void k_main(
    const float4* __restrict__ nf4, const float4* __restrict__ g4,
    const float* __restrict__ invc, const float* __restrict__ mask,
    const float4* __restrict__ Wcomb4, const float* __restrict__ bmW,
    const float* __restrict__ ba, float* __restrict__ out) {
  __shared__ float sA[128 * 33];   // [node][k] pad 33 -> a-reads conflict-free
  __shared__ float sB[32 * 64];    // [k][j]
  int tid = threadIdx.x;
  int ty = tid >> 3, tx = tid & 7;
  int nbase = blockIdx.x * 128;
  float acc[4][8];
#pragma unroll
  for (int r = 0; r < 4; ++r)
#pragma unroll
    for (int e = 0; e < 8; ++e) acc[r][e] = 0.f;

  for (int c = 0; c < 5; ++c) {
#pragma unroll
    for (int i = 0; i < 4; ++i) {
      int f = i * 256 + tid;          // 0..1023 float4s
      int nl = f >> 3, q = f & 7;
      int node = nbase + nl; if (node > NN - 1) node = NN - 1;
      float4 v;
      if (c < 2) {
        v = nf4[node * 16 + c * 8 + q];
      } else {
        v = g4[node * 24 + (c - 2) * 8 + q];
        float iv = invc[node];
        v.x *= iv; v.y *= iv; v.z *= iv; v.w *= iv;
      }
      float* p = &sA[nl * 33 + q * 4];
      p[0] = v.x; p[1] = v.y; p[2] = v.z; p[3] = v.w;
    }
#pragma unroll
    for (int i = 0; i < 2; ++i) {
      int f = i * 256 + tid;          // 0..511 float4s
      int kk = f >> 4, j4 = f & 15;
      float4 w = Wcomb4[(c * 32 + kk) * 16 + j4];
      *(float4*)&sB[kk * 64 + j4 * 4] = w;
    }
    __syncthreads();
#pragma unroll 8
    for (int kk = 0; kk < 32; ++kk) {
      float4 b0 = *(const float4*)&sB[kk * 64 + tx * 8];
      float4 b1 = *(const float4*)&sB[kk * 64 + tx * 8 + 4];
#pragma unroll
      for (int r = 0; r < 4; ++r) {
        float a = sA[(ty * 4 + r) * 33 + kk];
        acc[r][0] += a * b0.x; acc[r][1] += a * b0.y;
        acc[r][2] += a * b0.z; acc[r][3] += a * b0.w;
        acc[r][4] += a * b1.x; acc[r][5] += a * b1.y;
        acc[r][6] += a * b1.z; acc[r][7] += a * b1.w;
      }
    }
    __syncthreads();
  }
  float4 ba0 = ((const float4*)ba)[tx * 2];
  float4 ba1 = ((const float4*)ba)[tx * 2 + 1];
  float4 bw0 = ((const float4*)bmW)[tx * 2];
  float4 bw1 = ((const float4*)bmW)[tx * 2 + 1];
#pragma unroll
  for (int r = 0; r < 4; ++r) {
    int node = nbase + ty * 4 + r;
    if (node < NN) {
      float mk = mask[node];
      float4 o0, o1;
      o0.x = acc[r][0] + ba0.x + mk * bw0.x;
      o0.y = acc[r][1] + ba0.y + mk * bw0.y;
      o0.z = acc[r][2] + ba0.z + mk * bw0.z;
      o0.w = acc[r][3] + ba0.w + mk * bw0.w;
      o1.x = acc[r][4] + ba1.x + mk * bw1.x;
      o1.y = acc[r][5] + ba1.y + mk * bw1.y;
      o1.z = acc[r][6] + ba1.z + mk * bw1.z;
      o1.w = acc[r][7] + ba1.w + mk * bw1.w;
      o0.x = fmaxf(o0.x, 0.f); o0.y = fmaxf(o0.y, 0.f);
      o0.z = fmaxf(o0.z, 0.f); o0.w = fmaxf(o0.w, 0.f);
      o1.x = fmaxf(o1.x, 0.f); o1.y = fmaxf(o1.y, 0.f);
      o1.z = fmaxf(o1.z, 0.f); o1.w = fmaxf(o1.w, 0.f);
      *(float4*)&out[node * 64 + tx * 8] = o0;
      *(float4*)&out[node * 64 + tx * 8 + 4] = o1;
    }
  }
}

extern "C" void kernel_launch(void* const* d_in, const int* in_sizes, int n_in,
                              void* d_out, int out_size, void* d_ws, size_t ws_size,
                              hipStream_t stream) {
  const float* nf = (const float*)d_in[0];
  const float* ef = (const float*)d_in[1];
  const int*   src = (const int*)d_in[2];
  const int*   dst = (const int*)d_in[3];
  const float* Wm = (const float*)d_in[4];
  const float* bm = (const float*)d_in[5];
  const float* Wa = (const float*)d_in[6];
  const float* ba = (const float*)d_in[7];
  int*   wsi = (int*)d_ws;
  float* wsf = (float*)d_ws;
  int*   cnt    = wsi + OFF_CNT;
  int*   rs     = wsi + OFF_RS;
  int*   bsum   = wsi + OFF_BSUM;
  int2*  einfo  = (int2*)(wsi + OFF_EINFO);
  int*   hm     = wsi + OFF_HM;
  int*   om     = wsi + OFF_OM;
  float* g      = wsf + OFF_G;
  float* Wcomb  = wsf + OFF_WCOMB;
  float* bmW    = wsf + OFF_BMW;
  float* invc   = wsf + OFF_INV;
  float* mask   = wsf + OFF_MASK;
  float* out = (float*)d_out;

  hipMemsetAsync(cnt, 0, (size_t)NN * sizeof(int), stream);   // only histogram needs zeroing

  k_pre1<<<25, 256, 0, stream>>>(Wm, bm, Wa, Wcomb, bmW);
  k_hist<<<(NE / 8 + 255) / 256, 256, 0, stream>>>((const int4*)dst, cnt);
  k_scan1<<<NBLK, 256, 0, stream>>>(cnt, rs, bsum);
  k_scan2<<<1, 512, 0, stream>>>(bsum);
  k_scan3<<<NBLK, 256, 0, stream>>>(cnt, bsum, rs, invc, mask);
  k_bhist<<<NBLKE, 256, 0, stream>>>((const int4*)dst, hm);
  k_bscan<<<(NBIN * 64 + 255) / 256, 256, 0, stream>>>(hm, rs, om);
  k_bplace<<<NBLKE, 256, 0, stream>>>((const int4*)src, (const int4*)dst, om, einfo);
  k_sortbin<<<NBIN, 256, 0, stream>>>(rs, einfo);
  k_gather<<<NN / 4, 256, 0, stream>>>(nf, ef, einfo, rs, g);
  k_main<<<(NN + 127) / 128, 256, 0, stream>>>(
      (const float4*)nf, (const float4*)g, invc, mask,
      (const float4*)Wcomb, bmW, ba, out);
}

// Round 7
// 191.630 us; speedup vs baseline: 3.1758x; 1.3275x over previous
//
#include <hip/hip_runtime.h>

#define NN 100000      // nodes
#define NE 1600000     // edges
#define NBIN 782       // ceil(NN/128) bins (128 nodes each)
#define CAP  3072      // max edges per bin sortbin handles in LDS (+22 sigma)
#define EPB  8192      // edges per partition block
#define NBLKE 196      // ceil(NE/EPB)
// dims: NODE_IN=64, EDGE_DIM=32, NODE_OUT=64, concat=96, fused K=160

// ws layout (4B units) — no memset needed anywhere (all fully written first)
#define OFF_RS      0                  // NN+1  int   CSR row_start (built by sortbin)
#define OFF_BINSZ   100004             // NBIN  int   per-bin edge counts
#define OFF_BINBASE 100788             // NBIN+1 int  bin-level exclusive scan
#define OFF_MASK    101572             // NN    float cnt>0 ? 1 : 0 (built by sortbin)
#define OFF_EINFO   300520             // NE*2  int2  (src|dl<<20, eid) partitioned
#define OFF_G       3500520            // NN*96 float averaged concat sums (16B aligned)
#define OFF_HM      OFF_G              // NBLKE*NBIN int hist matrix (dead before g written)
#define OFF_OM      (OFF_G + 153272)   // NBLKE*NBIN int offset matrix (dead before g)
#define OFF_WCOMB   13100520           // 160*64 float [Wa_top(64x64); Wm@Wa_bot(96x64)]
#define OFF_BMW     13110760           // 64    float bm@Wa_bot

// ---- 1a. per-block bin histogram (radix partition phase A) --------------
__global__ __launch_bounds__(256) void k_bhist(const int4* __restrict__ dst4,
                                               int* __restrict__ hm) {
  __shared__ int h[NBIN];
  int b = blockIdx.x, t = threadIdx.x;
  for (int i = t; i < NBIN; i += 256) h[i] = 0;
  __syncthreads();
  int e0 = b * EPB;
#pragma unroll
  for (int i = 0; i < EPB / 1024; ++i) {
    int f = i * 256 + t;
    int e = e0 + f * 4;
    if (e < NE) {
      int4 d = dst4[(e0 >> 2) + f];
      atomicAdd(&h[d.x >> 7], 1);
      atomicAdd(&h[d.y >> 7], 1);
      atomicAdd(&h[d.z >> 7], 1);
      atomicAdd(&h[d.w >> 7], 1);
    }
  }
  __syncthreads();
  for (int i = t; i < NBIN; i += 256) hm[b * NBIN + i] = h[i];
}

// ---- 1b. column scan: om[b][bin] = sum_{b'<b} hm[b'][bin]; binsz[bin] ----
__global__ __launch_bounds__(256) void k_bscan(const int* __restrict__ hm,
                                               int* __restrict__ om,
                                               int* __restrict__ binsz) {
  int w = (blockIdx.x * 256 + threadIdx.x) >> 6;   // wave id == bin
  int lane = threadIdx.x & 63;
  if (w >= NBIN) return;
  int carry = 0;
  for (int base = 0; base < NBLKE; base += 64) {
    int b = base + lane;
    int v = (b < NBLKE) ? hm[b * NBIN + w] : 0;
    int inc = v;
#pragma unroll
    for (int off = 1; off < 64; off <<= 1) {
      int x = __shfl_up(inc, off);
      if (lane >= off) inc += x;
    }
    if (b < NBLKE) om[b * NBIN + w] = carry + inc - v;
    carry += __shfl(inc, 63);
  }
  if (lane == 0) binsz[w] = carry;
}

// ---- 1c. bin-level exclusive scan (one block) ----------------------------
__global__ __launch_bounds__(1024) void k_binscan(const int* __restrict__ binsz,
                                                  int* __restrict__ binbase) {
  __shared__ int s[1024];
  int t = threadIdx.x;
  int v = (t < NBIN) ? binsz[t] : 0;
  s[t] = v; __syncthreads();
#pragma unroll
  for (int off = 1; off < 1024; off <<= 1) {
    int x = (t >= off) ? s[t - off] : 0;
    __syncthreads();
    s[t] += x;
    __syncthreads();
  }
  if (t <= NBIN) binbase[t] = s[t] - v;   // v==0 for t>=NBIN -> binbase[NBIN]=NE
}

// ---- 2. place: LDS counting-sort by bin, write line-dense runs -----------
__global__ __launch_bounds__(256) void k_bplace(
    const int4* __restrict__ src4, const int4* __restrict__ dst4,
    const int* __restrict__ om, const int* __restrict__ binbase,
    int2* __restrict__ einfo) {
  __shared__ int2 buf[EPB];        // 64KB locally-sorted records
  __shared__ int hstart[1024];     // local exclusive bin starts (zero-padded)
  __shared__ int hcur[1024];       // counts, then cursors
  __shared__ int obase[NBIN];      // global run base for this block
  __shared__ int tscan[256];
  int b = blockIdx.x, t = threadIdx.x;
  int e0 = b * EPB;
  for (int i = t; i < 1024; i += 256) hcur[i] = 0;
  for (int i = t; i < NBIN; i += 256) obase[i] = binbase[i] + om[b * NBIN + i];
  __syncthreads();
  // pass 1: local bin histogram
#pragma unroll
  for (int i = 0; i < EPB / 1024; ++i) {
    int f = i * 256 + t;
    int e = e0 + f * 4;
    if (e < NE) {
      int4 d = dst4[(e0 >> 2) + f];
      atomicAdd(&hcur[d.x >> 7], 1);
      atomicAdd(&hcur[d.y >> 7], 1);
      atomicAdd(&hcur[d.z >> 7], 1);
      atomicAdd(&hcur[d.w >> 7], 1);
    }
  }
  __syncthreads();
  // exclusive scan of 1024 buckets: 4/thread serial + Hillis-Steele on sums
  int base4 = t * 4;
  int v0 = hcur[base4], v1 = hcur[base4 + 1], v2 = hcur[base4 + 2], v3 = hcur[base4 + 3];
  int s = v0 + v1 + v2 + v3;
  tscan[t] = s;
  __syncthreads();
#pragma unroll
  for (int off = 1; off < 256; off <<= 1) {
    int x = (t >= off) ? tscan[t - off] : 0;
    __syncthreads();
    tscan[t] += x;
    __syncthreads();
  }
  int texcl = tscan[t] - s;
  hstart[base4]     = texcl;
  hstart[base4 + 1] = texcl + v0;
  hstart[base4 + 2] = texcl + v0 + v1;
  hstart[base4 + 3] = texcl + v0 + v1 + v2;
  __syncthreads();
  for (int i = t; i < 1024; i += 256) hcur[i] = hstart[i];
  __syncthreads();
  // pass 2: place records at sorted local positions (bin in y bits 21..31)
#pragma unroll
  for (int i = 0; i < EPB / 1024; ++i) {
    int f = i * 256 + t;
    int e = e0 + f * 4;
    if (e < NE) {
      int4 d = dst4[(e0 >> 2) + f];
      int4 sv = src4[(e0 >> 2) + f];
      int p0 = atomicAdd(&hcur[d.x >> 7], 1);
      int p1 = atomicAdd(&hcur[d.y >> 7], 1);
      int p2 = atomicAdd(&hcur[d.z >> 7], 1);
      int p3 = atomicAdd(&hcur[d.w >> 7], 1);
      buf[p0] = make_int2(sv.x | ((d.x & 127) << 20), (e)     | ((d.x >> 7) << 21));
      buf[p1] = make_int2(sv.y | ((d.y & 127) << 20), (e + 1) | ((d.y >> 7) << 21));
      buf[p2] = make_int2(sv.z | ((d.z & 127) << 20), (e + 2) | ((d.z >> 7) << 21));
      buf[p3] = make_int2(sv.w | ((d.w & 127) << 20), (e + 3) | ((d.w >> 7) << 21));
    }
  }
  __syncthreads();
  // write out: local-sorted order -> contiguous global runs per bin
  int nE = NE - e0; if (nE > EPB) nE = EPB;
  for (int i = t; i < nE; i += 256) {
    int2 r = buf[i];
    int bin = (unsigned)r.y >> 21;
    int pos = obase[bin] + (i - hstart[bin]);
    einfo[pos] = make_int2(r.x, r.y & 0x1FFFFF);
  }
}

// ---- 3. per-bin counting sort into CSR order; emits rs + mask ------------
__global__ __launch_bounds__(256) void k_sortbin(const int* __restrict__ binbase,
                                                 int* __restrict__ rs,
                                                 float* __restrict__ mask,
                                                 int2* __restrict__ einfo) {
  __shared__ int hist[128];
  __shared__ int excl[128];
  __shared__ int2 buf[CAP];
  int b = blockIdx.x, t = threadIdx.x;
  int base = binbase[b];
  int nE = binbase[b + 1] - base;
  int nS = nE < CAP ? nE : CAP;       // statistically nE << CAP always
  if (t < 128) hist[t] = 0;
  __syncthreads();
  for (int i = t; i < nS; i += 256) {  // load + per-node count
    int2 v = einfo[base + i];
    buf[i] = v;
    atomicAdd(&hist[(v.x >> 20) & 127], 1);
  }
  __syncthreads();
  int myc = 0;
  if (t < 128) { myc = hist[t]; excl[t] = myc; }
  __syncthreads();
#pragma unroll
  for (int off = 1; off < 128; off <<= 1) {  // Hillis-Steele inclusive scan
    int x = 0;
    if (t < 128 && t >= off) x = excl[t - off];
    __syncthreads();
    if (t < 128) excl[t] += x;
    __syncthreads();
  }
  if (t < 128) {
    int node = b * 128 + t;
    if (node < NN) {                    // emit CSR row_start + isolated mask
      rs[node] = base + excl[t] - myc;
      mask[node] = myc ? 1.f : 0.f;
    }
    hist[t] = t ? excl[t - 1] : 0;      // reuse hist as write cursor
  }
  if (b == NBIN - 1 && t == 0) rs[NN] = NE;
  __syncthreads();
  for (int i = t; i < nS; i += 256) {  // place in CSR order, strip packing
    int2 v = buf[i];
    int dl = (v.x >> 20) & 127;
    int p = atomicAdd(&hist[dl], 1);
    einfo[base + p] = make_int2(v.x & 0xFFFFF, v.y);
  }
  for (int i = nS + t; i < nE; i += 256)  // unreachable overflow: keep data sane
    atomicAnd((int*)&einfo[base + i].x, 0xFFFFF);
}

// ---- 4. gather: one wave per node; float2 loads (2 nf rows / 4 ef rows ----
// per load instruction via half-/quarter-wave pairing), 16-edge unroll.
// Writes g pre-averaged by 1/deg.
__global__ __launch_bounds__(256) void k_gather(
    const float2* __restrict__ nf2, const float2* __restrict__ ef2,
    const int2* __restrict__ einfo, const int* __restrict__ rs,
    float* __restrict__ g) {
  int wid = threadIdx.x >> 6, lane = threadIdx.x & 63;
  int node = blockIdx.x * 4 + wid;          // 25000*4 == NN exactly
  int beg = rs[node], end = rs[node + 1];
  int deg = end - beg;
  int h = lane >> 5, l32 = lane & 31;       // nf pairing: half -> edge j+h
  int q = lane >> 4, l16 = lane & 15;       // ef quads:   quarter -> edge j+q
  float a0x = 0.f, a0y = 0.f, a1x = 0.f, a1y = 0.f;
  for (int base = 0; base < deg; base += 64) {
    int nb = deg - base; if (nb > 64) nb = 64;
    int2 info = (lane < nb) ? einfo[beg + base + lane] : make_int2(0, 0);
    int j = 0;
    for (; j + 16 <= nb; j += 16) {
      int s0 = __shfl(info.x, j + h);
      int s1 = __shfl(info.x, j + 2 + h);
      int s2 = __shfl(info.x, j + 4 + h);
      int s3 = __shfl(info.x, j + 6 + h);
      int s4 = __shfl(info.x, j + 8 + h);
      int s5 = __shfl(info.x, j + 10 + h);
      int s6 = __shfl(info.x, j + 12 + h);
      int s7 = __shfl(info.x, j + 14 + h);
      int e0 = __shfl(info.y, j + q);
      int e1 = __shfl(info.y, j + 4 + q);
      int e2 = __shfl(info.y, j + 8 + q);
      int e3 = __shfl(info.y, j + 12 + q);
      float2 v0 = nf2[s0 * 32 + l32];
      float2 v1 = nf2[s1 * 32 + l32];
      float2 v2 = nf2[s2 * 32 + l32];
      float2 v3 = nf2[s3 * 32 + l32];
      float2 v4 = nf2[s4 * 32 + l32];
      float2 v5 = nf2[s5 * 32 + l32];
      float2 v6 = nf2[s6 * 32 + l32];
      float2 v7 = nf2[s7 * 32 + l32];
      float2 w0 = ef2[e0 * 16 + l16];
      float2 w1 = ef2[e1 * 16 + l16];
      float2 w2 = ef2[e2 * 16 + l16];
      float2 w3 = ef2[e3 * 16 + l16];
      a0x += (v0.x + v1.x) + (v2.x + v3.x) + (v4.x + v5.x) + (v6.x + v7.x);
      a0y += (v0.y + v1.y) + (v2.y + v3.y) + (v4.y + v5.y) + (v6.y + v7.y);
      a1x += (w0.x + w1.x) + (w2.x + w3.x);
      a1y += (w0.y + w1.y) + (w2.y + w3.y);
    }
    for (; j + 4 <= nb; j += 4) {
      int s0 = __shfl(info.x, j + h);
      int s1 = __shfl(info.x, j + 2 + h);
      int e0 = __shfl(info.y, j + q);
      float2 v0 = nf2[s0 * 32 + l32];
      float2 v1 = nf2[s1 * 32 + l32];
      float2 w0 = ef2[e0 * 16 + l16];
      a0x += v0.x + v1.x; a0y += v0.y + v1.y;
      a1x += w0.x;        a1y += w0.y;
    }
    for (; j < nb; ++j) {              // 0-3 leftover edges, masked lanes
      int s0 = __shfl(info.x, j);
      int e0 = __shfl(info.y, j);
      if (h == 0) { float2 v = nf2[s0 * 32 + l32]; a0x += v.x; a0y += v.y; }
      if (q == 0) { float2 w = ef2[e0 * 16 + l16]; a1x += w.x; a1y += w.y; }
    }
  }
  // fold partials: halves for a0, quarters for a1
  a0x += __shfl_xor(a0x, 32); a0y += __shfl_xor(a0y, 32);
  a1x += __shfl_xor(a1x, 16); a1y += __shfl_xor(a1y, 16);
  a1x += __shfl_xor(a1x, 32); a1y += __shfl_xor(a1y, 32);
  float inv = deg > 0 ? 1.f / (float)deg : 0.f;
  if (lane < 32) {
    *(float2*)&g[node * 96 + lane * 2] = make_float2(a0x * inv, a0y * inv);
  } else if (lane < 48) {
    *(float2*)&g[node * 96 + 64 + l16 * 2] = make_float2(a1x * inv, a1y * inv);
  }
}

// ---- precompute fused weights: Wcomb = [Wa[0:64]; Wm @ Wa[64:128]] ------
__global__ __launch_bounds__(256) void k_pre1(
    const float* __restrict__ Wm, const float* __restrict__ bm,
    const float* __restrict__ Wa, float* __restrict__ Wcomb,
    float* __restrict__ bmW) {
  int b = blockIdx.x, t = threadIdx.x;
  if (b < 24) {                       // 24*256 = 6144 = 96*64 fused entries
    int o = b * 256 + t;
    int k = o >> 6, j = o & 63;
    float acc = 0.f;
    for (int kk = 0; kk < 64; ++kk)
      acc += Wm[k * 64 + kk] * Wa[(64 + kk) * 64 + j];
    Wcomb[(64 + k) * 64 + j] = acc;
  } else {
    for (int i = t; i < 64 * 64; i += 256) Wcomb[i] = Wa[i];  // top block copy
    if (t < 64) {
      float acc = 0.f;
      for (int kk = 0; kk < 64; ++kk) acc += bm[kk] * Wa[(64 + kk) * 64 + t];
      bmW[t] = acc;
    }
  }
}

// ---- fused node GEMM: out = relu([nf | g] @ Wcomb + ba + mask*bmW) ------
// block: 128 nodes x 64 outs; thread: 4 nodes x 8 outs; K=160 in 5 chunks of 32.
__global__ __launch_bounds__(256) void k_main(
    const float4* __restrict__ nf4, const float4* __restrict__ g4,
    const float* __restrict__ mask,
    const float4* __restrict__ Wcomb4, const float* __restrict__ bmW,
    const float* __restrict__ ba, float* __restrict__ out) {
  __shared__ float sA[128 * 33];   // [node][k] pad 33 -> a-reads conflict-free
  __shared__ float sB[32 * 64];    // [k][j]
  int tid = threadIdx.x;
  int ty = tid >> 3, tx = tid & 7;
  int nbase = blockIdx.x * 128;
  float acc[4][8];
#pragma unroll
  for (int r = 0; r < 4; ++r)
#pragma unroll
    for (int e = 0; e < 8; ++e) acc[r][e] = 0.f;

  for (int c = 0; c < 5; ++c) {
#pragma unroll
    for (int i = 0; i < 4; ++i) {
      int f = i * 256 + tid;          // 0..1023 float4s
      int nl = f >> 3, q = f & 7;
      int node = nbase + nl; if (node > NN - 1) node = NN - 1;
      float4 v;
      if (c < 2) {
        v = nf4[node * 16 + c * 8 + q];
      } else {
        v = g4[node * 24 + (c - 2) * 8 + q];   // g pre-averaged by gather
      }
      float* p = &sA[nl * 33 + q * 4];
      p[0] = v.x; p[1] = v.y; p[2] = v.z; p[3] = v.w;
    }
#pragma unroll
    for (int i = 0; i < 2; ++i) {
      int f = i * 256 + tid;          // 0..511 float4s
      int kk = f >> 4, j4 = f & 15;
      float4 w = Wcomb4[(c * 32 + kk) * 16 + j4];
      *(float4*)&sB[kk * 64 + j4 * 4] = w;
    }
    __syncthreads();
#pragma unroll 8
    for (int kk = 0; kk < 32; ++kk) {
      float4 b0 = *(const float4*)&sB[kk * 64 + tx * 8];
      float4 b1 = *(const float4*)&sB[kk * 64 + tx * 8 + 4];
#pragma unroll
      for (int r = 0; r < 4; ++r) {
        float a = sA[(ty * 4 + r) * 33 + kk];
        acc[r][0] += a * b0.x; acc[r][1] += a * b0.y;
        acc[r][2] += a * b0.z; acc[r][3] += a * b0.w;
        acc[r][4] += a * b1.x; acc[r][5] += a * b1.y;
        acc[r][6] += a * b1.z; acc[r][7] += a * b1.w;
      }
    }
    __syncthreads();
  }
  float4 ba0 = ((const float4*)ba)[tx * 2];
  float4 ba1 = ((const float4*)ba)[tx * 2 + 1];
  float4 bw0 = ((const float4*)bmW)[tx * 2];
  float4 bw1 = ((const float4*)bmW)[tx * 2 + 1];
#pragma unroll
  for (int r = 0; r < 4; ++r) {
    int node = nbase + ty * 4 + r;
    if (node < NN) {
      float mk = mask[node];
      float4 o0, o1;
      o0.x = acc[r][0] + ba0.x + mk * bw0.x;
      o0.y = acc[r][1] + ba0.y + mk * bw0.y;
      o0.z = acc[r][2] + ba0.z + mk * bw0.z;
      o0.w = acc[r][3] + ba0.w + mk * bw0.w;
      o1.x = acc[r][4] + ba1.x + mk * bw1.x;
      o1.y = acc[r][5] + ba1.y + mk * bw1.y;
      o1.z = acc[r][6] + ba1.z + mk * bw1.z;
      o1.w = acc[r][7] + ba1.w + mk * bw1.w;
      o0.x = fmaxf(o0.x, 0.f); o0.y = fmaxf(o0.y, 0.f);
      o0.z = fmaxf(o0.z, 0.f); o0.w = fmaxf(o0.w, 0.f);
      o1.x = fmaxf(o1.x, 0.f); o1.y = fmaxf(o1.y, 0.f);
      o1.z = fmaxf(o1.z, 0.f); o1.w = fmaxf(o1.w, 0.f);
      *(float4*)&out[node * 64 + tx * 8] = o0;
      *(float4*)&out[node * 64 + tx * 8 + 4] = o1;
    }
  }
}

extern "C" void kernel_launch(void* const* d_in, const int* in_sizes, int n_in,
                              void* d_out, int out_size, void* d_ws, size_t ws_size,
                              hipStream_t stream) {
  const float* nf = (const float*)d_in[0];
  const float* ef = (const float*)d_in[1];
  const int*   src = (const int*)d_in[2];
  const int*   dst = (const int*)d_in[3];
  const float* Wm = (const float*)d_in[4];
  const float* bm = (const float*)d_in[5];
  const float* Wa = (const float*)d_in[6];
  const float* ba = (const float*)d_in[7];
  int*   wsi = (int*)d_ws;
  float* wsf = (float*)d_ws;
  int*   rs      = wsi + OFF_RS;
  int*   binsz   = wsi + OFF_BINSZ;
  int*   binbase = wsi + OFF_BINBASE;
  int2*  einfo   = (int2*)(wsi + OFF_EINFO);
  int*   hm      = wsi + OFF_HM;
  int*   om      = wsi + OFF_OM;
  float* mask    = wsf + OFF_MASK;
  float* g       = wsf + OFF_G;
  float* Wcomb   = wsf + OFF_WCOMB;
  float* bmW     = wsf + OFF_BMW;
  float* out = (float*)d_out;

  k_pre1<<<25, 256, 0, stream>>>(Wm, bm, Wa, Wcomb, bmW);
  k_bhist<<<NBLKE, 256, 0, stream>>>((const int4*)dst, hm);
  k_bscan<<<(NBIN * 64 + 255) / 256, 256, 0, stream>>>(hm, om, binsz);
  k_binscan<<<1, 1024, 0, stream>>>(binsz, binbase);
  k_bplace<<<NBLKE, 256, 0, stream>>>((const int4*)src, (const int4*)dst, om,
                                      binbase, einfo);
  k_sortbin<<<NBIN, 256, 0, stream>>>(binbase, rs, mask, einfo);
  k_gather<<<NN / 4, 256, 0, stream>>>((const float2*)nf, (const float2*)ef,
                                       einfo, rs, g);
  k_main<<<(NN + 127) / 128, 256, 0, stream>>>(
      (const float4*)nf, (const float4*)g, mask,
      (const float4*)Wcomb, bmW, ba, out);
}

// Round 9
// 178.631 us; speedup vs baseline: 3.4069x; 1.0728x over previous
//
#include <hip/hip_runtime.h>

#define NN 100000      // nodes
#define NE 1600000     // edges
#define NBIN 782       // ceil(NN/128) bins (128 nodes each)
#define CAP  3072      // max edges per bin sortbin handles in LDS (+22 sigma)
#define EPB  8192      // edges per partition block
#define NBLKE 196      // ceil(NE/EPB)
// dims: NODE_IN=64, EDGE_DIM=32, NODE_OUT=64, concat=96, fused K=160

// ws layout (4B units) — no memset needed anywhere (all fully written first)
#define OFF_RS      0                  // NN+1  int   CSR row_start (built by sortbin)
#define OFF_BINSZ   100004             // NBIN  int   per-bin edge counts
#define OFF_BINBASE 100788             // NBIN+1 int  bin-level exclusive scan
#define OFF_MASK    101572             // NN    float cnt>0 ? 1 : 0 (built by sortbin)
#define OFF_EINFO   300520             // NE*2  int2  (src|dl<<20, eid) partitioned
#define OFF_G       3500520            // NN*96 float averaged concat sums (16B aligned)
#define OFF_HM      OFF_G              // NBLKE*NBIN int hist matrix (dead before g written)
#define OFF_OM      (OFF_G + 153272)   // NBLKE*NBIN int offset matrix (dead before g)
#define OFF_WCOMB   13100520           // 160*64 float [Wa_top(64x64); Wm@Wa_bot(96x64)]
#define OFF_BMW     13110760           // 64    float bm@Wa_bot

// ---- 1a. per-block bin histogram (radix partition phase A) --------------
__global__ __launch_bounds__(256) void k_bhist(const int4* __restrict__ dst4,
                                               int* __restrict__ hm) {
  __shared__ int h[NBIN];
  int b = blockIdx.x, t = threadIdx.x;
  for (int i = t; i < NBIN; i += 256) h[i] = 0;
  __syncthreads();
  int e0 = b * EPB;
#pragma unroll
  for (int i = 0; i < EPB / 1024; ++i) {
    int f = i * 256 + t;
    int e = e0 + f * 4;
    if (e < NE) {
      int4 d = dst4[(e0 >> 2) + f];
      atomicAdd(&h[d.x >> 7], 1);
      atomicAdd(&h[d.y >> 7], 1);
      atomicAdd(&h[d.z >> 7], 1);
      atomicAdd(&h[d.w >> 7], 1);
    }
  }
  __syncthreads();
  for (int i = t; i < NBIN; i += 256) hm[b * NBIN + i] = h[i];
}

// ---- 1b. column scan: om[b][bin] = sum_{b'<b} hm[b'][bin]; binsz[bin] ----
__global__ __launch_bounds__(256) void k_bscan(const int* __restrict__ hm,
                                               int* __restrict__ om,
                                               int* __restrict__ binsz) {
  int w = (blockIdx.x * 256 + threadIdx.x) >> 6;   // wave id == bin
  int lane = threadIdx.x & 63;
  if (w >= NBIN) return;
  int carry = 0;
  for (int base = 0; base < NBLKE; base += 64) {
    int b = base + lane;
    int v = (b < NBLKE) ? hm[b * NBIN + w] : 0;
    int inc = v;
#pragma unroll
    for (int off = 1; off < 64; off <<= 1) {
      int x = __shfl_up(inc, off);
      if (lane >= off) inc += x;
    }
    if (b < NBLKE) om[b * NBIN + w] = carry + inc - v;
    carry += __shfl(inc, 63);
  }
  if (lane == 0) binsz[w] = carry;
}

// ---- 1c. bin-level exclusive scan (one block) ----------------------------
__global__ __launch_bounds__(1024) void k_binscan(const int* __restrict__ binsz,
                                                  int* __restrict__ binbase) {
  __shared__ int s[1024];
  int t = threadIdx.x;
  int v = (t < NBIN) ? binsz[t] : 0;
  s[t] = v; __syncthreads();
#pragma unroll
  for (int off = 1; off < 1024; off <<= 1) {
    int x = (t >= off) ? s[t - off] : 0;
    __syncthreads();
    s[t] += x;
    __syncthreads();
  }
  if (t <= NBIN) binbase[t] = s[t] - v;   // v==0 for t>=NBIN -> binbase[NBIN]=NE
}

// ---- 2. place: LDS counting-sort by bin, write line-dense runs -----------
__global__ __launch_bounds__(256) void k_bplace(
    const int4* __restrict__ src4, const int4* __restrict__ dst4,
    const int* __restrict__ om, const int* __restrict__ binbase,
    int2* __restrict__ einfo) {
  __shared__ int2 buf[EPB];        // 64KB locally-sorted records
  __shared__ int hstart[1024];     // local exclusive bin starts (zero-padded)
  __shared__ int hcur[1024];       // counts, then cursors
  __shared__ int obase[NBIN];      // global run base for this block
  __shared__ int tscan[256];
  int b = blockIdx.x, t = threadIdx.x;
  int e0 = b * EPB;
  for (int i = t; i < 1024; i += 256) hcur[i] = 0;
  for (int i = t; i < NBIN; i += 256) obase[i] = binbase[i] + om[b * NBIN + i];
  __syncthreads();
  // pass 1: local bin histogram
#pragma unroll
  for (int i = 0; i < EPB / 1024; ++i) {
    int f = i * 256 + t;
    int e = e0 + f * 4;
    if (e < NE) {
      int4 d = dst4[(e0 >> 2) + f];
      atomicAdd(&hcur[d.x >> 7], 1);
      atomicAdd(&hcur[d.y >> 7], 1);
      atomicAdd(&hcur[d.z >> 7], 1);
      atomicAdd(&hcur[d.w >> 7], 1);
    }
  }
  __syncthreads();
  // exclusive scan of 1024 buckets: 4/thread serial + Hillis-Steele on sums
  int base4 = t * 4;
  int v0 = hcur[base4], v1 = hcur[base4 + 1], v2 = hcur[base4 + 2], v3 = hcur[base4 + 3];
  int s = v0 + v1 + v2 + v3;
  tscan[t] = s;
  __syncthreads();
#pragma unroll
  for (int off = 1; off < 256; off <<= 1) {
    int x = (t >= off) ? tscan[t - off] : 0;
    __syncthreads();
    tscan[t] += x;
    __syncthreads();
  }
  int texcl = tscan[t] - s;
  hstart[base4]     = texcl;
  hstart[base4 + 1] = texcl + v0;
  hstart[base4 + 2] = texcl + v0 + v1;
  hstart[base4 + 3] = texcl + v0 + v1 + v2;
  __syncthreads();
  for (int i = t; i < 1024; i += 256) hcur[i] = hstart[i];
  __syncthreads();
  // pass 2: place records at sorted local positions (bin in y bits 21..31)
#pragma unroll
  for (int i = 0; i < EPB / 1024; ++i) {
    int f = i * 256 + t;
    int e = e0 + f * 4;
    if (e < NE) {
      int4 d = dst4[(e0 >> 2) + f];
      int4 sv = src4[(e0 >> 2) + f];
      int p0 = atomicAdd(&hcur[d.x >> 7], 1);
      int p1 = atomicAdd(&hcur[d.y >> 7], 1);
      int p2 = atomicAdd(&hcur[d.z >> 7], 1);
      int p3 = atomicAdd(&hcur[d.w >> 7], 1);
      buf[p0] = make_int2(sv.x | ((d.x & 127) << 20), (e)     | ((d.x >> 7) << 21));
      buf[p1] = make_int2(sv.y | ((d.y & 127) << 20), (e + 1) | ((d.y >> 7) << 21));
      buf[p2] = make_int2(sv.z | ((d.z & 127) << 20), (e + 2) | ((d.z >> 7) << 21));
      buf[p3] = make_int2(sv.w | ((d.w & 127) << 20), (e + 3) | ((d.w >> 7) << 21));
    }
  }
  __syncthreads();
  // write out: local-sorted order -> contiguous global runs per bin
  int nE = NE - e0; if (nE > EPB) nE = EPB;
  for (int i = t; i < nE; i += 256) {
    int2 r = buf[i];
    int bin = (unsigned)r.y >> 21;
    int pos = obase[bin] + (i - hstart[bin]);
    einfo[pos] = make_int2(r.x, r.y & 0x1FFFFF);
  }
}

// ---- 3. per-bin counting sort into CSR order; emits rs + mask ------------
__global__ __launch_bounds__(256) void k_sortbin(const int* __restrict__ binbase,
                                                 int* __restrict__ rs,
                                                 float* __restrict__ mask,
                                                 int2* __restrict__ einfo) {
  __shared__ int hist[128];
  __shared__ int excl[128];
  __shared__ int2 buf[CAP];
  int b = blockIdx.x, t = threadIdx.x;
  int base = binbase[b];
  int nE = binbase[b + 1] - base;
  int nS = nE < CAP ? nE : CAP;       // statistically nE << CAP always
  if (t < 128) hist[t] = 0;
  __syncthreads();
  for (int i = t; i < nS; i += 256) {  // load + per-node count
    int2 v = einfo[base + i];
    buf[i] = v;
    atomicAdd(&hist[(v.x >> 20) & 127], 1);
  }
  __syncthreads();
  int myc = 0;
  if (t < 128) { myc = hist[t]; excl[t] = myc; }
  __syncthreads();
#pragma unroll
  for (int off = 1; off < 128; off <<= 1) {  // Hillis-Steele inclusive scan
    int x = 0;
    if (t < 128 && t >= off) x = excl[t - off];
    __syncthreads();
    if (t < 128) excl[t] += x;
    __syncthreads();
  }
  if (t < 128) {
    int node = b * 128 + t;
    if (node < NN) {                    // emit CSR row_start + isolated mask
      rs[node] = base + excl[t] - myc;
      mask[node] = myc ? 1.f : 0.f;
    }
    hist[t] = t ? excl[t - 1] : 0;      // reuse hist as write cursor
  }
  if (b == NBIN - 1 && t == 0) rs[NN] = NE;
  __syncthreads();
  for (int i = t; i < nS; i += 256) {  // place in CSR order, strip packing
    int2 v = buf[i];
    int dl = (v.x >> 20) & 127;
    int p = atomicAdd(&hist[dl], 1);
    einfo[base + p] = make_int2(v.x & 0xFFFFF, v.y);
  }
  for (int i = nS + t; i < nE; i += 256)  // unreachable overflow: keep data sane
    atomicAnd((int*)&einfo[base + i].x, 0xFFFFF);
}

// ---- 4. gather: one wave per node, lane = feature dim --------------------
// All index broadcasts via __builtin_amdgcn_readlane (SGPR, no bpermute).
// ef pairs two edges per load instruction: lanes<32 take the even edge,
// lanes>=32 the odd edge, selected on already-broadcast scalars (VALU select).
// 16-edge unroll: 16 nf + 8 ef loads (~6KB) in flight. g written pre-averaged.
__global__ __launch_bounds__(256) void k_gather(
    const float* __restrict__ nf, const float* __restrict__ ef,
    const int2* __restrict__ einfo, const int* __restrict__ rs,
    float* __restrict__ g) {
  int wid = threadIdx.x >> 6, lane = threadIdx.x & 63;
  int node = blockIdx.x * 4 + wid;          // 25000*4 == NN exactly
  int beg = rs[node], end = rs[node + 1];
  int deg = end - beg;
  bool hi = lane >= 32;
  int l32 = lane & 31;
  float a0 = 0.f, a1 = 0.f;
  for (int base = 0; base < deg; base += 64) {
    int nb = deg - base; if (nb > 64) nb = 64;
    int2 info = (lane < nb) ? einfo[beg + base + lane] : make_int2(0, 0);
    int j = 0;
    for (; j + 16 <= nb; j += 16) {
      int s0  = __builtin_amdgcn_readlane(info.x, j);
      int s1  = __builtin_amdgcn_readlane(info.x, j + 1);
      int s2  = __builtin_amdgcn_readlane(info.x, j + 2);
      int s3  = __builtin_amdgcn_readlane(info.x, j + 3);
      int s4  = __builtin_amdgcn_readlane(info.x, j + 4);
      int s5  = __builtin_amdgcn_readlane(info.x, j + 5);
      int s6  = __builtin_amdgcn_readlane(info.x, j + 6);
      int s7  = __builtin_amdgcn_readlane(info.x, j + 7);
      int s8  = __builtin_amdgcn_readlane(info.x, j + 8);
      int s9  = __builtin_amdgcn_readlane(info.x, j + 9);
      int s10 = __builtin_amdgcn_readlane(info.x, j + 10);
      int s11 = __builtin_amdgcn_readlane(info.x, j + 11);
      int s12 = __builtin_amdgcn_readlane(info.x, j + 12);
      int s13 = __builtin_amdgcn_readlane(info.x, j + 13);
      int s14 = __builtin_amdgcn_readlane(info.x, j + 14);
      int s15 = __builtin_amdgcn_readlane(info.x, j + 15);
      int ep0 = hi ? __builtin_amdgcn_readlane(info.y, j + 1)
                   : __builtin_amdgcn_readlane(info.y, j);
      int ep1 = hi ? __builtin_amdgcn_readlane(info.y, j + 3)
                   : __builtin_amdgcn_readlane(info.y, j + 2);
      int ep2 = hi ? __builtin_amdgcn_readlane(info.y, j + 5)
                   : __builtin_amdgcn_readlane(info.y, j + 4);
      int ep3 = hi ? __builtin_amdgcn_readlane(info.y, j + 7)
                   : __builtin_amdgcn_readlane(info.y, j + 6);
      int ep4 = hi ? __builtin_amdgcn_readlane(info.y, j + 9)
                   : __builtin_amdgcn_readlane(info.y, j + 8);
      int ep5 = hi ? __builtin_amdgcn_readlane(info.y, j + 11)
                   : __builtin_amdgcn_readlane(info.y, j + 10);
      int ep6 = hi ? __builtin_amdgcn_readlane(info.y, j + 13)
                   : __builtin_amdgcn_readlane(info.y, j + 12);
      int ep7 = hi ? __builtin_amdgcn_readlane(info.y, j + 15)
                   : __builtin_amdgcn_readlane(info.y, j + 14);
      float v0  = nf[s0  * 64 + lane];
      float v1  = nf[s1  * 64 + lane];
      float v2  = nf[s2  * 64 + lane];
      float v3  = nf[s3  * 64 + lane];
      float v4  = nf[s4  * 64 + lane];
      float v5  = nf[s5  * 64 + lane];
      float v6  = nf[s6  * 64 + lane];
      float v7  = nf[s7  * 64 + lane];
      float v8  = nf[s8  * 64 + lane];
      float v9  = nf[s9  * 64 + lane];
      float v10 = nf[s10 * 64 + lane];
      float v11 = nf[s11 * 64 + lane];
      float v12 = nf[s12 * 64 + lane];
      float v13 = nf[s13 * 64 + lane];
      float v14 = nf[s14 * 64 + lane];
      float v15 = nf[s15 * 64 + lane];
      float w0 = ef[ep0 * 32 + l32];
      float w1 = ef[ep1 * 32 + l32];
      float w2 = ef[ep2 * 32 + l32];
      float w3 = ef[ep3 * 32 + l32];
      float w4 = ef[ep4 * 32 + l32];
      float w5 = ef[ep5 * 32 + l32];
      float w6 = ef[ep6 * 32 + l32];
      float w7 = ef[ep7 * 32 + l32];
      a0 += ((v0 + v1) + (v2 + v3)) + ((v4 + v5) + (v6 + v7))
          + ((v8 + v9) + (v10 + v11)) + ((v12 + v13) + (v14 + v15));
      a1 += ((w0 + w1) + (w2 + w3)) + ((w4 + w5) + (w6 + w7));
    }
    for (; j + 4 <= nb; j += 4) {
      int s0 = __builtin_amdgcn_readlane(info.x, j);
      int s1 = __builtin_amdgcn_readlane(info.x, j + 1);
      int s2 = __builtin_amdgcn_readlane(info.x, j + 2);
      int s3 = __builtin_amdgcn_readlane(info.x, j + 3);
      int ep0 = hi ? __builtin_amdgcn_readlane(info.y, j + 1)
                   : __builtin_amdgcn_readlane(info.y, j);
      int ep1 = hi ? __builtin_amdgcn_readlane(info.y, j + 3)
                   : __builtin_amdgcn_readlane(info.y, j + 2);
      float v0 = nf[s0 * 64 + lane];
      float v1 = nf[s1 * 64 + lane];
      float v2 = nf[s2 * 64 + lane];
      float v3 = nf[s3 * 64 + lane];
      float w0 = ef[ep0 * 32 + l32];
      float w1 = ef[ep1 * 32 + l32];
      a0 += (v0 + v1) + (v2 + v3);
      a1 += w0 + w1;
    }
    for (; j < nb; ++j) {              // 0-3 leftover edges
      int s0 = __builtin_amdgcn_readlane(info.x, j);
      int e0 = __builtin_amdgcn_readlane(info.y, j);
      a0 += nf[s0 * 64 + lane];
      if (!hi) a1 += ef[e0 * 32 + l32];
    }
  }
  a1 += __shfl_down(a1, 32);     // fold odd-edge ef sums (upper half) into lower
  float inv = deg > 0 ? 1.f / (float)deg : 0.f;
  g[node * 96 + lane] = a0 * inv;
  if (!hi) g[node * 96 + 64 + l32] = a1 * inv;
}

// ---- precompute fused weights: Wcomb = [Wa[0:64]; Wm @ Wa[64:128]] ------
__global__ __launch_bounds__(256) void k_pre1(
    const float* __restrict__ Wm, const float* __restrict__ bm,
    const float* __restrict__ Wa, float* __restrict__ Wcomb,
    float* __restrict__ bmW) {
  int b = blockIdx.x, t = threadIdx.x;
  if (b < 24) {                       // 24*256 = 6144 = 96*64 fused entries
    int o = b * 256 + t;
    int k = o >> 6, j = o & 63;
    float acc = 0.f;
    for (int kk = 0; kk < 64; ++kk)
      acc += Wm[k * 64 + kk] * Wa[(64 + kk) * 64 + j];
    Wcomb[(64 + k) * 64 + j] = acc;
  } else {
    for (int i = t; i < 64 * 64; i += 256) Wcomb[i] = Wa[i];  // top block copy
    if (t < 64) {
      float acc = 0.f;
      for (int kk = 0; kk < 64; ++kk) acc += bm[kk] * Wa[(64 + kk) * 64 + t];
      bmW[t] = acc;
    }
  }
}

// ---- fused node GEMM: out = relu([nf | g] @ Wcomb + ba + mask*bmW) ------
// block: 128 nodes x 64 outs; thread: 4 nodes x 8 outs; K=160 in 5 chunks of 32.
__global__ __launch_bounds__(256) void k_main(
    const float4* __restrict__ nf4, const float4* __restrict__ g4,
    const float* __restrict__ mask,
    const float4* __restrict__ Wcomb4, const float* __restrict__ bmW,
    const float* __restrict__ ba, float* __restrict__ out) {
  __shared__ float sA[128 * 33];   // [node][k] pad 33 -> a-reads conflict-free
  __shared__ float sB[32 * 64];    // [k][j]
  int tid = threadIdx.x;
  int ty = tid >> 3, tx = tid & 7;
  int nbase = blockIdx.x * 128;
  float acc[4][8];
#pragma unroll
  for (int r = 0; r < 4; ++r)
#pragma unroll
    for (int e = 0; e < 8; ++e) acc[r][e] = 0.f;

  for (int c = 0; c < 5; ++c) {
#pragma unroll
    for (int i = 0; i < 4; ++i) {
      int f = i * 256 + tid;          // 0..1023 float4s
      int nl = f >> 3, q = f & 7;
      int node = nbase + nl; if (node > NN - 1) node = NN - 1;
      float4 v;
      if (c < 2) {
        v = nf4[node * 16 + c * 8 + q];
      } else {
        v = g4[node * 24 + (c - 2) * 8 + q];   // g pre-averaged by gather
      }
      float* p = &sA[nl * 33 + q * 4];
      p[0] = v.x; p[1] = v.y; p[2] = v.z; p[3] = v.w;
    }
#pragma unroll
    for (int i = 0; i < 2; ++i) {
      int f = i * 256 + tid;          // 0..511 float4s
      int kk = f >> 4, j4 = f & 15;
      float4 w = Wcomb4[(c * 32 + kk) * 16 + j4];
      *(float4*)&sB[kk * 64 + j4 * 4] = w;
    }
    __syncthreads();
#pragma unroll 8
    for (int kk = 0; kk < 32; ++kk) {
      float4 b0 = *(const float4*)&sB[kk * 64 + tx * 8];
      float4 b1 = *(const float4*)&sB[kk * 64 + tx * 8 + 4];
#pragma unroll
      for (int r = 0; r < 4; ++r) {
        float a = sA[(ty * 4 + r) * 33 + kk];
        acc[r][0] += a * b0.x; acc[r][1] += a * b0.y;
        acc[r][2] += a * b0.z; acc[r][3] += a * b0.w;
        acc[r][4] += a * b1.x; acc[r][5] += a * b1.y;
        acc[r][6] += a * b1.z; acc[r][7] += a * b1.w;
      }
    }
    __syncthreads();
  }
  float4 ba0 = ((const float4*)ba)[tx * 2];
  float4 ba1 = ((const float4*)ba)[tx * 2 + 1];
  float4 bw0 = ((const float4*)bmW)[tx * 2];
  float4 bw1 = ((const float4*)bmW)[tx * 2 + 1];
#pragma unroll
  for (int r = 0; r < 4; ++r) {
    int node = nbase + ty * 4 + r;
    if (node < NN) {
      float mk = mask[node];
      float4 o0, o1;
      o0.x = acc[r][0] + ba0.x + mk * bw0.x;
      o0.y = acc[r][1] + ba0.y + mk * bw0.y;
      o0.z = acc[r][2] + ba0.z + mk * bw0.z;
      o0.w = acc[r][3] + ba0.w + mk * bw0.w;
      o1.x = acc[r][4] + ba1.x + mk * bw1.x;
      o1.y = acc[r][5] + ba1.y + mk * bw1.y;
      o1.z = acc[r][6] + ba1.z + mk * bw1.z;
      o1.w = acc[r][7] + ba1.w + mk * bw1.w;
      o0.x = fmaxf(o0.x, 0.f); o0.y = fmaxf(o0.y, 0.f);
      o0.z = fmaxf(o0.z, 0.f); o0.w = fmaxf(o0.w, 0.f);
      o1.x = fmaxf(o1.x, 0.f); o1.y = fmaxf(o1.y, 0.f);
      o1.z = fmaxf(o1.z, 0.f); o1.w = fmaxf(o1.w, 0.f);
      *(float4*)&out[node * 64 + tx * 8] = o0;
      *(float4*)&out[node * 64 + tx * 8 + 4] = o1;
    }
  }
}

extern "C" void kernel_launch(void* const* d_in, const int* in_sizes, int n_in,
                              void* d_out, int out_size, void* d_ws, size_t ws_size,
                              hipStream_t stream) {
  const float* nf = (const float*)d_in[0];
  const float* ef = (const float*)d_in[1];
  const int*   src = (const int*)d_in[2];
  const int*   dst = (const int*)d_in[3];
  const float* Wm = (const float*)d_in[4];
  const float* bm = (const float*)d_in[5];
  const float* Wa = (const float*)d_in[6];
  const float* ba = (const float*)d_in[7];
  int*   wsi = (int*)d_ws;
  float* wsf = (float*)d_ws;
  int*   rs      = wsi + OFF_RS;
  int*   binsz   = wsi + OFF_BINSZ;
  int*   binbase = wsi + OFF_BINBASE;
  int2*  einfo   = (int2*)(wsi + OFF_EINFO);
  int*   hm      = wsi + OFF_HM;
  int*   om      = wsi + OFF_OM;
  float* mask    = wsf + OFF_MASK;
  float* g       = wsf + OFF_G;
  float* Wcomb   = wsf + OFF_WCOMB;
  float* bmW     = wsf + OFF_BMW;
  float* out = (float*)d_out;

  k_pre1<<<25, 256, 0, stream>>>(Wm, bm, Wa, Wcomb, bmW);
  k_bhist<<<NBLKE, 256, 0, stream>>>((const int4*)dst, hm);
  k_bscan<<<(NBIN * 64 + 255) / 256, 256, 0, stream>>>(hm, om, binsz);
  k_binscan<<<1, 1024, 0, stream>>>(binsz, binbase);
  k_bplace<<<NBLKE, 256, 0, stream>>>((const int4*)src, (const int4*)dst, om,
                                      binbase, einfo);
  k_sortbin<<<NBIN, 256, 0, stream>>>(binbase, rs, mask, einfo);
  k_gather<<<NN / 4, 256, 0, stream>>>(nf, ef, einfo, rs, g);
  k_main<<<(NN + 127) / 128, 256, 0, stream>>>(
      (const float4*)nf, (const float4*)g, mask,
      (const float4*)Wcomb, bmW, ba, out);
}